// Round 1
// baseline (213.695 us; speedup 1.0000x reference)
//
#include <hip/hip_runtime.h>
#include <math.h>

// Normalization_60095182406123
//
// Reference = separable 4D Gaussian filter of x^2 over axes (freq, orient, y, x):
//   out[c,y,x] = sum_{df,do,dy,dx} g3[df] g3[do] g32[dy] g32[dx]
//                 * xsq[c + (df-1)*16 + (do-1)*2, y+dy-16, x+dx-16]
// with zero padding per-axis, c = img*192 + freq*16 + orient*2 + phase
// (identical flat channel indexing for input and output).
//
// Pass 1: x^2 + orient(3) + freq(3) + blur_x(32)   -> ws[c,y,x]
// Pass 2: blur_y(32)                               -> out[c,y,x]
//
// ws needs 768*224*224*4 = 154,140,672 bytes of d_ws.

#define SZW   224
#define PLANE (224*224)   // 50176
#define NCHB  96          // freq*orient channels per (img,phase)
#define PW    256         // padded LDS row width (16 zero | 224 data | 15 zero | 1 extra)

#define INV_SQRT_2PI 0.3989422804014327f

__global__ __launch_bounds__(512) void pass1_kernel(const float* __restrict__ in,
                                                    float* __restrict__ ws)
{
    __shared__ float s2[NCHB * PW];   // 96*256*4 = 98304 B

    const int tid   = threadIdx.x;
    const int y     = blockIdx.x;   // 0..223
    const int phase = blockIdx.y;   // 0..1
    const int img   = blockIdx.z;   // 0..3

    const float w31 = INV_SQRT_2PI;                  // g3 center
    const float w30 = INV_SQRT_2PI * expf(-0.5f);    // g3 edge

    const int ibase0 = (img*192 + phase) * PLANE + y * SZW;  // + (ch*2)*PLANE + x

    // ---- step 1: load x^2 (x-padded), orient 3-tap conv, store to LDS ----
    // unit u in [0,768): f = u>>6 (0..11), xp4 = u&63 (float4 column group)
    #pragma unroll
    for (int it = 0; it < 2; ++it) {
        int u = tid + it*512;
        if (u < 768) {
            int f   = u >> 6;
            int xp4 = u & 63;
            float4 a[8];
            if (xp4 >= 4 && xp4 < 60) {
                int x0 = xp4*4 - 16;   // 0..220, 16B-aligned, fully in-bounds
                #pragma unroll
                for (int o = 0; o < 8; ++o) {
                    float4 v = *reinterpret_cast<const float4*>(
                        in + ibase0 + (f*8 + o)*2*PLANE + x0);
                    a[o].x = v.x*v.x; a[o].y = v.y*v.y;
                    a[o].z = v.z*v.z; a[o].w = v.w*v.w;
                }
            } else {
                #pragma unroll
                for (int o = 0; o < 8; ++o) a[o] = make_float4(0.f,0.f,0.f,0.f);
            }
            #pragma unroll
            for (int o = 0; o < 8; ++o) {
                float4 l = (o > 0) ? a[o-1] : make_float4(0.f,0.f,0.f,0.f);
                float4 r = (o < 7) ? a[o+1] : make_float4(0.f,0.f,0.f,0.f);
                float4 b;
                b.x = fmaf(w31, a[o].x, w30*(l.x + r.x));
                b.y = fmaf(w31, a[o].y, w30*(l.y + r.y));
                b.z = fmaf(w31, a[o].z, w30*(l.z + r.z));
                b.w = fmaf(w31, a[o].w, w30*(l.w + r.w));
                *reinterpret_cast<float4*>(&s2[(f*8 + o)*PW + xp4*4]) = b;
            }
        }
    }
    __syncthreads();

    // ---- step 2: freq 3-tap conv, in place (each thread owns its columns) ----
    {
        int o   = tid >> 6;   // 0..7
        int xp4 = tid & 63;
        float4 a[12];
        #pragma unroll
        for (int f = 0; f < 12; ++f)
            a[f] = *reinterpret_cast<const float4*>(&s2[(f*8 + o)*PW + xp4*4]);
        #pragma unroll
        for (int f = 0; f < 12; ++f) {
            float4 l = (f > 0)  ? a[f-1] : make_float4(0.f,0.f,0.f,0.f);
            float4 r = (f < 11) ? a[f+1] : make_float4(0.f,0.f,0.f,0.f);
            float4 b;
            b.x = fmaf(w31, a[f].x, w30*(l.x + r.x));
            b.y = fmaf(w31, a[f].y, w30*(l.y + r.y));
            b.z = fmaf(w31, a[f].z, w30*(l.z + r.z));
            b.w = fmaf(w31, a[f].w, w30*(l.w + r.w));
            *reinterpret_cast<float4*>(&s2[(f*8 + o)*PW + xp4*4]) = b;
        }
    }
    __syncthreads();

    // ---- step 3: 32-tap blur along x, write ws ----
    float wx[32];
    #pragma unroll
    for (int k = 0; k < 32; ++k) {
        float t = fmaf((float)k, 2.0f/31.0f, -1.0f);
        wx[k] = INV_SQRT_2PI * expf(-0.5f*t*t);
    }

    // unit u in [0, 96*56): ch = u/56, xq = u%56, 4 outputs per unit
    for (int u = tid; u < NCHB*56; u += 512) {
        int ch = u / 56;
        int xq = u - ch*56;
        int x0 = xq * 4;
        float rv[36];
        const float4* p = reinterpret_cast<const float4*>(&s2[ch*PW + x0]);
        #pragma unroll
        for (int t = 0; t < 9; ++t) {
            float4 q = p[t];
            rv[4*t+0] = q.x; rv[4*t+1] = q.y; rv[4*t+2] = q.z; rv[4*t+3] = q.w;
        }
        float a0 = 0.f, a1 = 0.f, a2 = 0.f, a3 = 0.f;
        #pragma unroll
        for (int k = 0; k < 32; ++k) {
            a0 = fmaf(wx[k], rv[k+0], a0);
            a1 = fmaf(wx[k], rv[k+1], a1);
            a2 = fmaf(wx[k], rv[k+2], a2);
            a3 = fmaf(wx[k], rv[k+3], a3);
        }
        *reinterpret_cast<float4*>(ws + ibase0 + ch*2*PLANE + x0) =
            make_float4(a0, a1, a2, a3);
    }
}

__global__ __launch_bounds__(256) void pass2_kernel(const float* __restrict__ ws,
                                                    float* __restrict__ out)
{
    const int c = blockIdx.x;     // 0..767
    const int x = threadIdx.x;    // column
    if (x >= SZW) return;

    float wy[32];
    #pragma unroll
    for (int k = 0; k < 32; ++k) {
        float t = fmaf((float)k, 2.0f/31.0f, -1.0f);
        wy[k] = INV_SQRT_2PI * expf(-0.5f*t*t);
    }

    const float* col = ws  + c * PLANE + x;
    float*       oc  = out + c * PLANE + x;

    // rolling window: w[i] = row(y0 - 16 + i), 47 rows for 16 outputs/iter
    float w[47];
    #pragma unroll
    for (int i = 0; i < 47; ++i) {
        int yy = i - 16;
        w[i] = (yy >= 0 && yy < SZW) ? col[yy*SZW] : 0.f;
    }

    #pragma unroll 1
    for (int y0 = 0; y0 < SZW; y0 += 16) {
        float acc[16];
        #pragma unroll
        for (int j = 0; j < 16; ++j) acc[j] = 0.f;
        #pragma unroll
        for (int k = 0; k < 32; ++k) {
            #pragma unroll
            for (int j = 0; j < 16; ++j)
                acc[j] = fmaf(wy[k], w[j+k], acc[j]);
        }
        #pragma unroll
        for (int j = 0; j < 16; ++j) oc[(y0+j)*SZW] = acc[j];

        // shift window by 16, load next 16 rows (zero past the bottom)
        #pragma unroll
        for (int i = 0; i < 31; ++i) w[i] = w[i+16];
        #pragma unroll
        for (int i = 0; i < 16; ++i) {
            int yy = y0 + 31 + i;
            w[31+i] = (yy < SZW) ? col[yy*SZW] : 0.f;
        }
    }
}

extern "C" void kernel_launch(void* const* d_in, const int* in_sizes, int n_in,
                              void* d_out, int out_size, void* d_ws, size_t ws_size,
                              hipStream_t stream)
{
    const float* x  = (const float*)d_in[0];
    float*      out = (float*)d_out;
    float*      ws  = (float*)d_ws;   // needs 768*224*224*4 = 154,140,672 B

    dim3 g1(SZW, 2, 4);               // (y, phase, img)
    pass1_kernel<<<g1, 512, 0, stream>>>(x, ws);
    pass2_kernel<<<768, 256, 0, stream>>>(ws, out);
}

// Round 2
// 176.687 us; speedup vs baseline: 1.2095x; 1.2095x over previous
//
#include <hip/hip_runtime.h>
#include <math.h>

// Normalization_60095182406123
//
// Reference = separable 4D Gaussian filter of x^2 over axes (freq, orient, y, x):
//   out[c,y,x] = sum g3[df] g3[do] g32[dy] g32[dx] * xsq[c+(df-1)*16+(do-1)*2, y+dy-16, x+dx-16]
// c = img*192 + freq*16 + orient*2 + phase (same flat layout in and out).
//
// Pass 1: x^2 + orient(3) + freq(3) + blur_x(32) -> ws[c,y,x]
//   - freq axis split 3-way across blocks (4 output freqs + 1 halo each side)
//   - LDS 48 rows x 260 floats = 49,920 B -> 3 blocks/CU, 24 waves/CU
// Pass 2: blur_y(32) -> out[c,y,x]
//
// ws needs 768*224*224*4 = 154,140,672 bytes of d_ws.

#define SZW   224
#define PLANE (224*224)
#define PW    260          // padded LDS row width in floats (16 zero | 224 | 15 zero | pad)

#define INV_SQRT_2PI 0.3989422804014327f

__global__ __launch_bounds__(512, 6) void pass1_kernel(const float* __restrict__ in,
                                                       float* __restrict__ ws)
{
    __shared__ float s2[48 * PW];   // 49,920 B

    const int tid   = threadIdx.x;
    const int y     = blockIdx.x;          // 0..223
    const int by    = blockIdx.y;          // 0..5
    const int phase = by & 1;
    const int fg    = by >> 1;             // freq group: output f in [4fg, 4fg+4)
    const int img   = blockIdx.z;          // 0..3

    const float w31 = INV_SQRT_2PI;                 // g3 center
    const float w30 = INV_SQRT_2PI * expf(-0.5f);   // g3 edge

    // ---- step 1: load x^2 (x-padded, freq f = 4fg-1+lf), orient 3-tap, to LDS ----
    if (tid < 384) {
        const int lf  = tid >> 6;          // 0..5
        const int xp4 = tid & 63;          // float4 column group
        const int f   = 4*fg - 1 + lf;     // -1..12
        float4 a[8];
        if (f >= 0 && f < 12 && xp4 >= 4 && xp4 < 60) {
            const int x0 = xp4*4 - 16;     // 0..220, 16B-aligned
            const float* base = in + (img*192 + f*16 + phase)*PLANE + y*SZW + x0;
            #pragma unroll
            for (int o = 0; o < 8; ++o) {
                float4 v = *reinterpret_cast<const float4*>(base + o*2*PLANE);
                a[o].x = v.x*v.x; a[o].y = v.y*v.y;
                a[o].z = v.z*v.z; a[o].w = v.w*v.w;
            }
        } else {
            #pragma unroll
            for (int o = 0; o < 8; ++o) a[o] = make_float4(0.f,0.f,0.f,0.f);
        }
        #pragma unroll
        for (int o = 0; o < 8; ++o) {
            float4 l = (o > 0) ? a[o-1] : make_float4(0.f,0.f,0.f,0.f);
            float4 r = (o < 7) ? a[o+1] : make_float4(0.f,0.f,0.f,0.f);
            float4 b;
            b.x = fmaf(w31, a[o].x, w30*(l.x + r.x));
            b.y = fmaf(w31, a[o].y, w30*(l.y + r.y));
            b.z = fmaf(w31, a[o].z, w30*(l.z + r.z));
            b.w = fmaf(w31, a[o].w, w30*(l.w + r.w));
            *reinterpret_cast<float4*>(&s2[(lf*8 + o)*PW + xp4*4]) = b;
        }
    }
    __syncthreads();

    // ---- step 2: freq 3-tap conv in place (thread owns its (o, xp4) column) ----
    {
        const int o   = tid >> 6;          // 0..7
        const int xp4 = tid & 63;
        float4 a[6];
        #pragma unroll
        for (int lf = 0; lf < 6; ++lf)
            a[lf] = *reinterpret_cast<const float4*>(&s2[(lf*8 + o)*PW + xp4*4]);
        #pragma unroll
        for (int lf = 1; lf < 5; ++lf) {
            float4 b;
            b.x = fmaf(w31, a[lf].x, w30*(a[lf-1].x + a[lf+1].x));
            b.y = fmaf(w31, a[lf].y, w30*(a[lf-1].y + a[lf+1].y));
            b.z = fmaf(w31, a[lf].z, w30*(a[lf-1].z + a[lf+1].z));
            b.w = fmaf(w31, a[lf].w, w30*(a[lf-1].w + a[lf+1].w));
            *reinterpret_cast<float4*>(&s2[(lf*8 + o)*PW + xp4*4]) = b;
        }
    }
    __syncthreads();

    // ---- step 3: 32-tap blur along x, write ws ----
    float wx[32];
    #pragma unroll
    for (int k = 0; k < 32; ++k) {
        float t = fmaf((float)k, 2.0f/31.0f, -1.0f);
        wx[k] = INV_SQRT_2PI * expf(-0.5f*t*t);
    }

    const int obase = (img*192 + phase)*PLANE + y*SZW;

    // units: 32 output rows (lf 1..4, o 0..7) x 56 float4 groups = 1792
    for (int u = tid; u < 32*56; u += 512) {
        const int r  = u / 56;             // 0..31
        const int xq = u - r*56;
        const int lf = 1 + (r >> 3);
        const int o  = r & 7;
        const int f  = 4*fg + (r >> 3);
        const int x0 = xq * 4;
        const float4* p = reinterpret_cast<const float4*>(&s2[(lf*8 + o)*PW + x0]);
        float acc0 = 0.f, acc1 = 0.f, acc2 = 0.f, acc3 = 0.f;
        #pragma unroll
        for (int t = 0; t < 9; ++t) {
            float4 q = p[t];
            #pragma unroll
            for (int j = 0; j < 4; ++j) {
                const int m = 4*t + j;     // window index 0..35
                const float qv = (j==0)?q.x:(j==1)?q.y:(j==2)?q.z:q.w;
                if (m - 0 >= 0 && m - 0 < 32) acc0 = fmaf(wx[m-0], qv, acc0);
                if (m - 1 >= 0 && m - 1 < 32) acc1 = fmaf(wx[m-1], qv, acc1);
                if (m - 2 >= 0 && m - 2 < 32) acc2 = fmaf(wx[m-2], qv, acc2);
                if (m - 3 >= 0 && m - 3 < 32) acc3 = fmaf(wx[m-3], qv, acc3);
            }
        }
        *reinterpret_cast<float4*>(ws + obase + (f*16 + o*2)*PLANE + x0) =
            make_float4(acc0, acc1, acc2, acc3);
    }
}

__global__ __launch_bounds__(256) void pass2_kernel(const float* __restrict__ ws,
                                                    float* __restrict__ out)
{
    const int c = blockIdx.x;     // 0..767
    const int x = threadIdx.x;    // column
    if (x >= SZW) return;

    float wy[32];
    #pragma unroll
    for (int k = 0; k < 32; ++k) {
        float t = fmaf((float)k, 2.0f/31.0f, -1.0f);
        wy[k] = INV_SQRT_2PI * expf(-0.5f*t*t);
    }

    const float* col = ws  + c * PLANE + x;
    float*       oc  = out + c * PLANE + x;

    float w[47];
    #pragma unroll
    for (int i = 0; i < 47; ++i) {
        int yy = i - 16;
        w[i] = (yy >= 0 && yy < SZW) ? col[yy*SZW] : 0.f;
    }

    #pragma unroll 1
    for (int y0 = 0; y0 < SZW; y0 += 16) {
        float acc[16];
        #pragma unroll
        for (int j = 0; j < 16; ++j) acc[j] = 0.f;
        #pragma unroll
        for (int k = 0; k < 32; ++k) {
            #pragma unroll
            for (int j = 0; j < 16; ++j)
                acc[j] = fmaf(wy[k], w[j+k], acc[j]);
        }
        #pragma unroll
        for (int j = 0; j < 16; ++j) oc[(y0+j)*SZW] = acc[j];

        #pragma unroll
        for (int i = 0; i < 31; ++i) w[i] = w[i+16];
        #pragma unroll
        for (int i = 0; i < 16; ++i) {
            int yy = y0 + 31 + i;
            w[31+i] = (yy < SZW) ? col[yy*SZW] : 0.f;
        }
    }
}

extern "C" void kernel_launch(void* const* d_in, const int* in_sizes, int n_in,
                              void* d_out, int out_size, void* d_ws, size_t ws_size,
                              hipStream_t stream)
{
    const float* x  = (const float*)d_in[0];
    float*      out = (float*)d_out;
    float*      ws  = (float*)d_ws;   // 768*224*224*4 = 154,140,672 B

    dim3 g1(SZW, 6, 4);               // (y, phase*freqgroup, img)
    pass1_kernel<<<g1, 512, 0, stream>>>(x, ws);
    pass2_kernel<<<768, 256, 0, stream>>>(ws, out);
}